// Round 5
// baseline (1807.953 us; speedup 1.0000x reference)
//
#include <hip/hip_runtime.h>
#include <math.h>

// ---------------------------------------------------------------------------
// Net_LV Monte-Carlo local-vol simulation, MI355X (gfx950)
// 256 blocks x 512 threads. Each WAVE independently owns 16 paths end-to-end:
// no block barriers inside the step loop (intra-wave lockstep + in-order LDS
// pipe). Lanes = 4 path-groups x 16 neuron-groups; packed f32 (v_pk_fma_f32).
// Barriers only at period boundaries (weight reload + reductions).
// ---------------------------------------------------------------------------

#define TPB 512
#define NBLK 256
#define MC 32768
#define NSTEPS 90
#define NGRID 91
#define RATEf 0.025f

typedef float v4f __attribute__((ext_vector_type(4)));

__device__ __forceinline__ v4f splat4(float s) { return (v4f){s, s, s, s}; }
__device__ __forceinline__ v4f zero4() { return (v4f){0.f, 0.f, 0.f, 0.f}; }

// ---- d_out offsets (float elements), in reference return order ----
#define PATH_OFF   0
#define VARP_OFF   (MC*NGRID)
#define DL_OFF     (2*MC*NGRID)
#define PV_OFF     (2*MC*NGRID + MC)
#define VV_OFF     (PV_OFF + 63)
#define EP_OFF     (VV_OFF + 63)
#define MEAN_OFF   (EP_OFF + MC)
#define VAR_OFF    (MEAN_OFF + 1)
#define ERR_OFF    (VAR_OFF + 1)

// ---- workspace layout (doubles): per-block partial sums ----
#define WS_STRIDE  132
#define MEANE_SLOT (NBLK*WS_STRIDE)

// ---- LDS offsets (dwords) ----
enum : int {
  OFF_DW0 = 0,        // diff Wi row0 (t), padded 52
  OFF_DW1 = 52,
  OFF_DBI = 104,
  OFF_DWO = 156,      // padded 52 (rows 50,51 = 0)
  OFF_DBO = 208,
  OFF_DWH = 212,      // 3 * [50][52] (cols 50,51 = 0)
  OFF_DBH = 8012,     // 3 * [52]
  OFF_VW0 = 8168,     // cvv, padded 32
  OFF_VW1 = 8200,
  OFF_VBI = 8232,
  OFF_VWH = 8264,     // 2 * [30][32]
  OFF_VBH = 10184,    // 2 * [32]
  OFF_VWO = 10248,    // [30][64] (col 63 pad)
  OFF_VBO = 12168,    // [64]
  OFF_EBI = 12232,    // [24 pad]
  OFF_EWH = 12256,    // 2 * [20][20]
  OFF_EBH = 13056,    // 2 * [20]
  OFF_EWO = 13096,    // [20]
  OFF_EBO = 13116,    // (pad to 13120)
  OFF_EWI = 13120,    // [3][92][20] = 5520
  OFF_H   = 18640,    // per-wave H: 8 * [52][16]
  OFF_S   = 25296,    // per-wave S[16]
  OFF_G   = 25424,    // per-wave g[16]
  OFF_PSUM= 25552,    // 8 waves * 42 doubles = 672 dw
  OFF_ESUM= 26224,    // 8 waves * 4 doubles = 64 dw
  SMEM_DW = 26288
};
#define SMEM_BYTES (SMEM_DW*4)

#define CFENCE()  asm volatile("" ::: "memory")

__device__ __forceinline__ float softplus_f(float x) {
  return fmaxf(x, 0.0f) + log1pf(expf(-fabsf(x)));
}

// In-place hidden layer (per-wave private H, [rows][16] layout).
// Reads rows 0..K-1, writes rows j0..j0+NJ-1, relu. Safe without barriers:
// wave-lockstep => all read instrs issue before write instrs; per-wave LDS
// pipe is in-order. CFENCE pins compiler ordering.
template<int K, int WS, int NJ>
__device__ __forceinline__ void hidden_ip(float* sm, int Hb, int wb, int bb,
                                          int p4, int j0, bool act)
{
  v4f acc[NJ];
#pragma unroll
  for (int n = 0; n < NJ; ++n) acc[n] = zero4();
  if (act) {
#pragma unroll 5
    for (int k = 0; k < K; ++k) {
      const v4f x = *(const v4f*)&sm[Hb + k*16 + p4];
      if constexpr (NJ == 4) {
        const v4f w = *(const v4f*)&sm[wb + k*WS + j0];
        acc[0] = __builtin_elementwise_fma(splat4(w.x), x, acc[0]);
        acc[1] = __builtin_elementwise_fma(splat4(w.y), x, acc[1]);
        acc[2] = __builtin_elementwise_fma(splat4(w.z), x, acc[2]);
        acc[3] = __builtin_elementwise_fma(splat4(w.w), x, acc[3]);
      } else {
        const float2 w = *(const float2*)&sm[wb + k*WS + j0];
        acc[0] = __builtin_elementwise_fma(splat4(w.x), x, acc[0]);
        acc[1] = __builtin_elementwise_fma(splat4(w.y), x, acc[1]);
      }
    }
  }
  CFENCE();
  if (act) {
#pragma unroll
    for (int n = 0; n < NJ; ++n) {
      const v4f v = __builtin_elementwise_max(acc[n] + splat4(sm[bb + j0 + n]),
                                              zero4());
      *(v4f*)&sm[Hb + (j0+n)*16 + p4] = v;
    }
  }
  CFENCE();
}

// Full diff net (2->50->50->50->50->1, softplus), per-wave (16 paths).
// Returns d for path (lane&15) on all lanes.
__device__ __forceinline__ float diff_net(float* sm, float tp, int Hb, int Sb,
                                          int p4, int ng, int pl, int kq)
{
  { // L1 -> H rows 0..51 (rows 50,51 compute to 0 via padded weights)
    const v4f S4 = *(const v4f*)&sm[Sb + p4];
    if (ng < 13) {
#pragma unroll
      for (int jj = 0; jj < 4; ++jj) {
        const int j = 4*ng + jj;
        const float c = fmaf(sm[OFF_DW0 + j], tp, sm[OFF_DBI + j]);
        v4f v = __builtin_elementwise_fma(splat4(sm[OFF_DW1 + j]), S4, splat4(c));
        v = __builtin_elementwise_max(v, zero4());
        *(v4f*)&sm[Hb + j*16 + p4] = v;
      }
    }
  }
  CFENCE();
  hidden_ip<50,52,4>(sm, Hb, OFF_DWH,        OFF_DBH,       p4, 4*ng, ng < 13);
  hidden_ip<50,52,4>(sm, Hb, OFF_DWH + 2600, OFF_DBH + 52,  p4, 4*ng, ng < 13);
  hidden_ip<50,52,4>(sm, Hb, OFF_DWH + 5200, OFF_DBH + 104, p4, 4*ng, ng < 13);
  // output 50->1: split-k over 4 quarters (13 k's each; rows 50,51 & DWO pads = 0)
  float s = 0.0f;
#pragma unroll
  for (int kk = 0; kk < 13; ++kk) {
    const int k = kq*13 + kk;
    s = fmaf(sm[Hb + k*16 + pl], sm[OFF_DWO + k], s);
  }
  s += __shfl_xor(s, 16); s += __shfl_xor(s, 32);
  return softplus_f(s + sm[OFF_DBO]);
}

__device__ void load_weights(float* sm, int m, int tid,
  const float* dWi, const float* dbi_g, const float* dWh_g, const float* dbh_g,
  const float* dWo_g, const float* dbo_g,
  const float* vWi, const float* vbi_g, const float* vWh_g, const float* vbh_g,
  const float* vWo_g, const float* vbo_g,
  const float* ebi_g, const float* eWh_g, const float* ebh_g,
  const float* eWo_g, const float* ebo_g)
{
  for (int j = tid; j < 52; j += TPB) {
    sm[OFF_DW0+j] = (j<50) ? dWi[m*100 + j]      : 0.0f;
    sm[OFF_DW1+j] = (j<50) ? dWi[m*100 + 50 + j] : 0.0f;
    sm[OFF_DBI+j] = (j<50) ? dbi_g[m*50 + j]     : 0.0f;
    sm[OFF_DWO+j] = (j<50) ? dWo_g[m*50 + j]     : 0.0f;
  }
  for (int idx = tid; idx < 7800; idx += TPB) {
    const int l = idx / 2600, r = idx % 2600, k = r / 52, j = r % 52;
    sm[OFF_DWH+idx] = (j<50) ? dWh_g[((m*3+l)*50 + k)*50 + j] : 0.0f;
  }
  for (int idx = tid; idx < 156; idx += TPB) {
    const int l = idx/52, j = idx%52;
    sm[OFF_DBH+idx] = (j<50) ? dbh_g[(m*3+l)*50 + j] : 0.0f;
  }
  for (int j = tid; j < 32; j += TPB) {
    sm[OFF_VW0+j] = (j<30) ? vWi[m*60 + j]      : 0.0f;
    sm[OFF_VW1+j] = (j<30) ? vWi[m*60 + 30 + j] : 0.0f;
    sm[OFF_VBI+j] = (j<30) ? vbi_g[m*30 + j]    : 0.0f;
    sm[OFF_EBI+j] = (j<20) ? ebi_g[m*20 + j]    : 0.0f;
  }
  for (int idx = tid; idx < 1920; idx += TPB) {
    const int l = idx/960, r = idx%960, k = r/32, j = r%32;
    sm[OFF_VWH+idx] = (j<30) ? vWh_g[((m*2+l)*30 + k)*30 + j] : 0.0f;
  }
  for (int idx = tid; idx < 64; idx += TPB) {
    const int l = idx/32, j = idx%32;
    sm[OFF_VBH+idx] = (j<30) ? vbh_g[(m*2+l)*30 + j] : 0.0f;
  }
  for (int idx = tid; idx < 1920; idx += TPB) {
    const int k = idx/64, j = idx%64;
    sm[OFF_VWO+idx] = (j<63) ? vWo_g[(m*30 + k)*63 + j] : 0.0f;
  }
  for (int j = tid; j < 64; j += TPB)
    sm[OFF_VBO+j] = (j<63) ? vbo_g[m*63 + j] : 0.0f;
  for (int idx = tid; idx < 800; idx += TPB) {
    const int l = idx/400, r = idx%400, k = r/20, j = r%20;
    sm[OFF_EWH+idx] = eWh_g[((m*2+l)*20 + k)*20 + j];
  }
  for (int idx = tid; idx < 40; idx += TPB) {
    const int l = idx/20, j = idx%20;
    sm[OFF_EBH+idx] = ebh_g[(m*2+l)*20 + j];
  }
  for (int j = tid; j < 20; j += TPB)
    sm[OFF_EWO+j] = eWo_g[m*20 + j];
  if (tid == 0) { sm[OFF_DBO] = dbo_g[m]; sm[OFF_EBO] = ebo_g[m]; }
}

extern "C" __global__ void __launch_bounds__(TPB, 1)
sim_kernel(const float* __restrict__ S0g, const float* __restrict__ zg,
           const float* dWi, const float* dbi_g, const float* dWh_g,
           const float* dbh_g, const float* dWo_g, const float* dbo_g,
           const float* vWi, const float* vbi_g, const float* vWh_g,
           const float* vbh_g, const float* vWo_g, const float* vbo_g,
           const float* eWi, const float* ebi_g, const float* eWh_g,
           const float* ebh_g, const float* eWo_g, const float* ebo_g,
           float* __restrict__ out, double* __restrict__ wsd)
{
  extern __shared__ float sm[];
  const int tid  = threadIdx.x;
  const int wv   = tid >> 6;          // wave 0..7 (independent unit, 16 paths)
  const int lane = tid & 63;
  const int pg   = lane & 3;          // path group 0..3
  const int ng   = lane >> 2;         // neuron-tile index 0..15
  const int p4   = pg * 4;
  const int pl   = lane & 15;         // path 0..15 (per-path phases)
  const int kq   = lane >> 4;         // k-quarter 0..3
  const int Hb = OFF_H + wv * 832;    // [52][16]
  const int Sb = OFF_S + wv * 16;
  const int Gb = OFF_G + wv * 16;
  const int P0 = blockIdx.x * 128 + wv * 16;
  const float S0v = S0g[0];

  // cve_Wi for all 3 period nets ([3][92][20]) — loaded once
  for (int idx = tid; idx < 5520; idx += TPB) sm[OFF_EWI + idx] = eWi[idx];

  v4f cvv[4];   // cols 4ng..4ng+3 x paths p4..p4+3
#pragma unroll
  for (int b = 0; b < 4; ++b) cvv[b] = zero4();
  float S = S0v, rmax = S0v, cve = 0.0f;

  if (kq == 0) {
    sm[Sb + pl] = S0v;
    out[PATH_OFF + (size_t)(P0 + pl) * NGRID + 0] = S0v;
  }
  __syncthreads();   // EWI + Sb ready

  // incremental cve-L1 accumulators: lane owns (path pl, rows kq*5..kq*5+4)
  float accCur[5], accN[5], accN2[5];
#pragma unroll
  for (int jj = 0; jj < 5; ++jj) {
    const int r1 = 20 + kq*5 + jj;    // EWI row 1 (path[0] term)
    accCur[jj] = S0v * sm[OFF_EWI + 0*1840 + r1];
    accN[jj]   = S0v * sm[OFF_EWI + 1*1840 + r1];
    accN2[jj]  = S0v * sm[OFF_EWI + 2*1840 + r1];
  }

  for (int m = 0; m < 3; ++m) {
    if (m > 0) {
#pragma unroll
      for (int jj = 0; jj < 5; ++jj) { accCur[jj] = accN[jj]; accN[jj] = accN2[jj]; }
    }
    __syncthreads();   // all waves done with prior-period weights / psum read
    load_weights(sm, m, tid, dWi, dbi_g, dWh_g, dbh_g, dWo_g, dbo_g,
                 vWi, vbi_g, vWh_g, vbh_g, vWo_g, vbo_g,
                 ebi_g, eWh_g, ebh_g, eWo_g, ebo_g);
    __syncthreads();

    if (m == 0) {   // d0 / var0
      const float d0 = diff_net(sm, 0.0f, Hb, Sb, p4, ng, pl, kq);
      if (kq == 0)
        out[VARP_OFF + (size_t)(P0 + pl) * NGRID + 0] = d0 * d0;
    }

    for (int it = 1; it <= 30; ++it) {
      const int i = m*30 + it;
      const float ti = 0.01f * (float)i;
      const float tp = 0.01f * (float)(i - 1);
      const float hstep = ti - tp;
      const float sqh = sqrtf(hstep);
      const float disc = expf(-RATEf * tp);
      const float zval = zg[(size_t)(P0 + pl) * NSTEPS + (i - 1)];
      const float dWv = sqh * zval;

      // ---------------- diff net (no barriers) ----------------
      const float d = diff_net(sm, tp, Hb, Sb, p4, ng, pl, kq);
      const float g = ((disc * S) * d) * dWv;   // S is old S

      // per-path writes (g to LDS; varp/DL to global)
      if (kq == 0) {
        sm[Gb + pl] = g;
        out[VARP_OFF + (size_t)(P0 + pl) * NGRID + i] = d * d;
        if (i == NSTEPS) out[DL_OFF + (P0 + pl)] = d;
      }
      // ---- vL1 -> H rows 0..29 (after diff-out reads: program order) ----
      {
        const v4f S4 = *(const v4f*)&sm[Sb + p4];
        if (ng < 15) {
#pragma unroll
          for (int jj = 0; jj < 2; ++jj) {
            const int j = 2*ng + jj;
            const float c = fmaf(sm[OFF_VW0 + j], tp, sm[OFF_VBI + j]);
            v4f v = __builtin_elementwise_fma(splat4(sm[OFF_VW1 + j]), S4, splat4(c));
            v = __builtin_elementwise_max(v, zero4());
            *(v4f*)&sm[Hb + j*16 + p4] = v;
          }
        }
      }
      CFENCE();
      hidden_ip<30,32,2>(sm, Hb, OFF_VWH,       OFF_VBH,      p4, 2*ng, ng < 15);
      hidden_ip<30,32,2>(sm, Hb, OFF_VWH + 960, OFF_VBH + 32, p4, 2*ng, ng < 15);

      // ---- vOut (reads H rows 0..29 + Gb) then eL1 (writes rows 0..19) ----
      {
        v4f vacc[4];
#pragma unroll
        for (int b = 0; b < 4; ++b) vacc[b] = zero4();
        const int j0v = 4*ng;
#pragma unroll 5
        for (int k = 0; k < 30; ++k) {
          const v4f x = *(const v4f*)&sm[Hb + k*16 + p4];
          const v4f w = *(const v4f*)&sm[OFF_VWO + k*64 + j0v];
          vacc[0] = __builtin_elementwise_fma(splat4(w.x), x, vacc[0]);
          vacc[1] = __builtin_elementwise_fma(splat4(w.y), x, vacc[1]);
          vacc[2] = __builtin_elementwise_fma(splat4(w.z), x, vacc[2]);
          vacc[3] = __builtin_elementwise_fma(splat4(w.w), x, vacc[3]);
        }
        const v4f g4 = *(const v4f*)&sm[Gb + p4];
        CFENCE();   // vOut reads precede eL1 writes
        { // eL1: rows kq*5..kq*5+4, col pl
          const int ewb = OFF_EWI + m*1840;
#pragma unroll
          for (int jj = 0; jj < 5; ++jj) {
            const int j = kq*5 + jj;
            const float v = fmaf(sm[ewb + j], tp, accCur[jj] + sm[OFF_EBI + j]);
            sm[Hb + j*16 + pl] = fmaxf(v, 0.0f);
          }
        }
        CFENCE();
#pragma unroll
        for (int jj = 0; jj < 4; ++jj) {
          cvv[jj] = __builtin_elementwise_fma(
              g4, vacc[jj] + splat4(sm[OFF_VBO + j0v + jj]), cvv[jj]);
        }
      }
      hidden_ip<20,20,2>(sm, Hb, OFF_EWH,       OFF_EBH,      p4, 2*ng, ng < 10);
      hidden_ip<20,20,2>(sm, Hb, OFF_EWH + 400, OFF_EBH + 20, p4, 2*ng, ng < 10);

      // ---- eOut (rows 0..19), cve, state update, acc updates ----
      float oute;
      {
        float s_ = 0.0f;
#pragma unroll
        for (int kk = 0; kk < 5; ++kk) {
          const int k = kq*5 + kk;
          s_ = fmaf(sm[Hb + k*16 + pl], sm[OFF_EWO + k], s_);
        }
        s_ += __shfl_xor(s_, 16); s_ += __shfl_xor(s_, 32);
        oute = s_ + sm[OFF_EBO];
      }
      cve = fmaf(g, oute, cve);

      const float Sold = S;
      const float t1 = (RATEf*Sold*hstep) / (1.0f + (RATEf*Sold)*sqh);
      const float t2 = ((Sold*d)*dWv)     / (1.0f + (Sold*d)*sqh);
      const float Snew = (Sold + t1) + t2;
      S = Snew;
      rmax = fmaxf(rmax, Snew);
      if (kq == 0) {
        out[PATH_OFF + (size_t)(P0 + pl) * NGRID + i] = Snew;
        sm[Sb + pl] = Snew;   // in-order pipe: next-step L1 read sees it
      }
      { // incremental cve-L1 update with EWI row (1+i)
        const int roff = (1 + i)*20 + kq*5;
        const int bm = m*1840;
        const int bn = (m < 2 ? m + 1 : 2) * 1840;
#pragma unroll
        for (int jj = 0; jj < 5; ++jj) {
          accCur[jj] = fmaf(Snew, sm[OFF_EWI + bm   + roff + jj], accCur[jj]);
          accN[jj]   = fmaf(Snew, sm[OFF_EWI + bn   + roff + jj], accN[jj]);
          accN2[jj]  = fmaf(Snew, sm[OFF_EWI + 3680 + roff + jj], accN2[jj]);
        }
      }
      CFENCE();
    } // steps

    // ---------------- period-end price partials (per wave) ----------------
    {
      const float discm = expf(-RATEf * (0.01f * (float)(30*(m+1))));
      double* ps = (double*)&sm[OFF_PSUM];
#pragma unroll
      for (int cc = 0; cc < 4; ++cc) {
        const int col = 4*ng + cc;
        const bool actp = (col >= 21*m) && (col < 21*m + 21);
        double s1 = 0.0, s2 = 0.0;
        if (actp) {
          const float Kst = 0.8f + 0.02f * (float)(col - 21*m);
#pragma unroll
          for (int l = 0; l < 4; ++l) {
            const float Sp = sm[Sb + p4 + l];
            const float pr_ = discm * fmaxf(Sp - Kst, 0.0f) - cvv[cc][l];
            s1 += (double)pr_;
            s2 += (double)pr_ * (double)pr_;
          }
        }
        // sum over the 4 path-groups (lanes sharing ng: xor 1,2)
        s1 += __shfl_xor(s1, 1); s1 += __shfl_xor(s1, 2);
        s2 += __shfl_xor(s2, 1); s2 += __shfl_xor(s2, 2);
        if (actp && pg == 0) {
          const int sI = col - 21*m;
          ps[wv*42 + sI*2 + 0] = s1;
          ps[wv*42 + sI*2 + 1] = s2;
        }
      }
    }
    __syncthreads();
    if (tid < 21) {
      double* ps = (double*)&sm[OFF_PSUM];
      double a = 0.0, b = 0.0;
      for (int w = 0; w < 8; ++w) { a += ps[w*42 + tid*2]; b += ps[w*42 + tid*2 + 1]; }
      wsd[(size_t)blockIdx.x*WS_STRIDE + (m*21+tid)*2 + 0] = a;
      wsd[(size_t)blockIdx.x*WS_STRIDE + (m*21+tid)*2 + 1] = b;
    }
  } // periods

  // ---------------- exotic outputs & partials ----------------
  const float discT = expf(-RATEf * (0.01f * 90.0f));
  const float e  = discT * (rmax - S);
  const float ep = e - cve;
  if (kq == 0) out[EP_OFF + (P0 + pl)] = ep;
  double de  = (kq == 0) ? (double)e  : 0.0;
  double dp  = (kq == 0) ? (double)ep : 0.0;
  double dp2 = (kq == 0) ? (double)ep * (double)ep : 0.0;
#pragma unroll
  for (int msk = 1; msk <= 32; msk <<= 1) {
    de  += __shfl_xor(de,  msk);
    dp  += __shfl_xor(dp,  msk);
    dp2 += __shfl_xor(dp2, msk);
  }
  {
    double* es = (double*)&sm[OFF_ESUM];
    if (lane == 0) { es[wv*4+0] = de; es[wv*4+1] = dp; es[wv*4+2] = dp2; }
  }
  __syncthreads();
  if (tid == 0) {
    double* es = (double*)&sm[OFF_ESUM];
    double a = 0, b = 0, c = 0;
    for (int w = 0; w < 8; ++w) { a += es[w*4]; b += es[w*4+1]; c += es[w*4+2]; }
    wsd[(size_t)blockIdx.x*WS_STRIDE + 126] = a;
    wsd[(size_t)blockIdx.x*WS_STRIDE + 127] = b;
    wsd[(size_t)blockIdx.x*WS_STRIDE + 128] = c;
  }
}

extern "C" __global__ void finalize_kernel(double* __restrict__ wsd,
                                           float* __restrict__ out)
{
  const int t = threadIdx.x;
  if (t < 63) {
    double a = 0.0, b = 0.0;
    for (int blk = 0; blk < NBLK; ++blk) {
      a += wsd[(size_t)blk*WS_STRIDE + t*2 + 0];
      b += wsd[(size_t)blk*WS_STRIDE + t*2 + 1];
    }
    const double mean = a / (double)MC;
    const double var  = (b - a*a/(double)MC) / (double)(MC - 1);
    out[PV_OFF + t] = (float)mean;
    out[VV_OFF + t] = (float)var;
  } else if (t == 64) {
    double a = 0.0;
    for (int blk = 0; blk < NBLK; ++blk) a += wsd[(size_t)blk*WS_STRIDE + 126];
    wsd[MEANE_SLOT] = a / (double)MC;
  } else if (t == 65) {
    double a = 0.0, c = 0.0;
    for (int blk = 0; blk < NBLK; ++blk) {
      a += wsd[(size_t)blk*WS_STRIDE + 127];
      c += wsd[(size_t)blk*WS_STRIDE + 128];
    }
    out[MEAN_OFF] = (float)(a / (double)MC);
    out[VAR_OFF]  = (float)((c - a*a/(double)MC) / (double)(MC - 1));
  }
}

extern "C" __global__ void error_kernel(const double* __restrict__ wsd,
                                        float* __restrict__ out)
{
  const int p = blockIdx.x * 256 + threadIdx.x;
  if (p < MC) {
    const float meanE = (float)wsd[MEANE_SLOT];
    out[ERR_OFF + p] = out[EP_OFF + p] - meanE;
  }
}

extern "C" void kernel_launch(void* const* d_in, const int* in_sizes, int n_in,
                              void* d_out, int out_size, void* d_ws, size_t ws_size,
                              hipStream_t stream)
{
  (void)in_sizes; (void)n_in; (void)out_size; (void)ws_size;
  const float* S0g  = (const float*)d_in[0];
  const float* zg   = (const float*)d_in[1];
  // d_in[2..4] = MC_samples / ind_T / period_length (fixed constants)
  const float* dWi  = (const float*)d_in[5];
  const float* dbi  = (const float*)d_in[6];
  const float* dWh  = (const float*)d_in[7];
  const float* dbh  = (const float*)d_in[8];
  const float* dWo  = (const float*)d_in[9];
  const float* dbo  = (const float*)d_in[10];
  const float* vWi  = (const float*)d_in[11];
  const float* vbi  = (const float*)d_in[12];
  const float* vWh  = (const float*)d_in[13];
  const float* vbh  = (const float*)d_in[14];
  const float* vWo  = (const float*)d_in[15];
  const float* vbo  = (const float*)d_in[16];
  const float* eWi  = (const float*)d_in[17];
  const float* ebi  = (const float*)d_in[18];
  const float* eWh  = (const float*)d_in[19];
  const float* ebh  = (const float*)d_in[20];
  const float* eWo  = (const float*)d_in[21];
  const float* ebo  = (const float*)d_in[22];
  float* out  = (float*)d_out;
  double* wsd = (double*)d_ws;

  hipFuncSetAttribute(reinterpret_cast<const void*>(sim_kernel),
                      hipFuncAttributeMaxDynamicSharedMemorySize, SMEM_BYTES);

  sim_kernel<<<NBLK, TPB, SMEM_BYTES, stream>>>(
      S0g, zg, dWi, dbi, dWh, dbh, dWo, dbo,
      vWi, vbi, vWh, vbh, vWo, vbo,
      eWi, ebi, eWh, ebh, eWo, ebo, out, wsd);
  finalize_kernel<<<1, 128, 0, stream>>>(wsd, out);
  error_kernel<<<MC/256, 256, 0, stream>>>(wsd, out);
}

// Round 6
// 694.069 us; speedup vs baseline: 2.6049x; 2.6049x over previous
//
#include <hip/hip_runtime.h>
#include <math.h>

// ---------------------------------------------------------------------------
// Net_LV Monte-Carlo local-vol simulation, MI355X (gfx950)  — MFMA version
// 256 blocks x 512 threads. Each WAVE independently owns 16 paths end-to-end;
// zero block barriers in the step loop. All hidden layers + vOut run on the
// matrix cores via v_mfma_f32_16x16x32_f16 with 2-term f16 hi/lo splits
// (3 MFMAs per tile: Ah*Bh + Ah*Bl + Al*Bh, error ~2^-22).
// Activations: f16 hi/lo [path][k], stride 64 f16 (128B), XOR-swizzled.
// L1 layers / output dots / cve-L1 (incremental) stay VALU f32.
// ---------------------------------------------------------------------------

#define TPB 512
#define NBLK 256
#define MC 32768
#define NSTEPS 90
#define NGRID 91
#define RATEf 0.025f

typedef _Float16 f16;
typedef f16 f16x8 __attribute__((ext_vector_type(8)));
typedef f16 f16x4 __attribute__((ext_vector_type(4)));
typedef float f32x4 __attribute__((ext_vector_type(4)));

#define CFENCE() asm volatile("" ::: "memory")

// ---- d_out offsets (float elements), in reference return order ----
#define PATH_OFF   0
#define VARP_OFF   (MC*NGRID)
#define DL_OFF     (2*MC*NGRID)
#define PV_OFF     (2*MC*NGRID + MC)
#define VV_OFF     (PV_OFF + 63)
#define EP_OFF     (VV_OFF + 63)
#define MEAN_OFF   (EP_OFF + MC)
#define VAR_OFF    (MEAN_OFF + 1)
#define ERR_OFF    (VAR_OFF + 1)

// ---- workspace (doubles) ----
#define WS_STRIDE  132
#define MEANE_SLOT (NBLK*WS_STRIDE)

// ---- LDS f32 offsets (dwords) ----
enum : int {
  OFF_DW0 = 0,     // diff Wi t-row, padded 64
  OFF_DW1 = 64,
  OFF_DBI = 128,
  OFF_DWO = 192,
  OFF_DBH = 256,   // 3*64
  OFF_VW0 = 448,   // padded 32
  OFF_VW1 = 480,
  OFF_VBI = 512,
  OFF_VBH = 544,   // 2*32
  OFF_VBO = 608,   // 64
  OFF_EBI = 672,   // 32
  OFF_EBH = 704,   // 2*32
  OFF_EWO = 768,   // 32
  OFF_SC  = 800,   // [0]=dbo, [1]=ebo  (pad to 804)
  OFF_EWI = 804,   // f32 [3][92][20] = 5520 (+32 pad) = 5552
  OFF_PSUM= 6356,  // 8 waves * 42 doubles = 672 dw
  OFF_ESUM= 7028,  // 8 waves * 4 doubles = 64 dw
  F16BASE = 7092
};
// ---- f16 offsets (units of f16, relative to smh) ----
enum : int {
  DWH_HI_F = 0,        // 3 * [64][64] swizzled
  DWH_LO_F = 12288,
  VWH_F    = 24576,    // 2 * { hi[32][40], lo[32][40] }
  VWO_HI_F = 29696,    // [64][40]
  VWO_LO_F = 32256,
  EWH_F    = 34816,    // 2 * { hi[32][40], lo[32][40] }
  ACT_F    = 39936     // per wave: hi[16][64] + lo[16][64] = 2048
};
#define SMEM_DW   35252
#define SMEM_BYTES (SMEM_DW*4)

__device__ __forceinline__ float softplus_f(float x) {
  return fmaxf(x, 0.0f) + log1pf(expf(-fabsf(x)));
}

// MFMA hidden layer, in-place on act (f16 hi/lo, [path][k] swizzled).
// MT row-tiles of 16, KT k-tiles of 32. A: SWZ ? stride-64 swizzled : stride-40.
// p = lane&15 (path / A-row), g = lane>>4 (k-slot group), sw = (p&7)<<3.
template<int MT, int KT, bool SWZ>
__device__ __forceinline__ void mfma_hidden(
    const f16* __restrict__ Ah, const f16* __restrict__ Al,
    f16* acth, f16* actl, const float* __restrict__ bias,
    int p, int g, int sw)
{
  f16x8 Bh[KT], Bl[KT];
#pragma unroll
  for (int kt = 0; kt < KT; ++kt) {
    const int bi = p*64 + ((32*kt + 8*g) ^ sw);
    Bh[kt] = *(const f16x8*)&acth[bi];
    Bl[kt] = *(const f16x8*)&actl[bi];
  }
  f32x4 acc[MT];
#pragma unroll
  for (int mt = 0; mt < MT; ++mt) acc[mt] = (f32x4){0.f,0.f,0.f,0.f};
#pragma unroll
  for (int mt = 0; mt < MT; ++mt) {
#pragma unroll
    for (int kt = 0; kt < KT; ++kt) {
      const int row = p + 16*mt;
      const int ai = SWZ ? row*64 + ((32*kt + 8*g) ^ sw)
                         : row*40 + 32*kt + 8*g;
      const f16x8 ah = *(const f16x8*)&Ah[ai];
      const f16x8 al = *(const f16x8*)&Al[ai];
      acc[mt] = __builtin_amdgcn_mfma_f32_16x16x32_f16(al, Bh[kt], acc[mt], 0,0,0);
      acc[mt] = __builtin_amdgcn_mfma_f32_16x16x32_f16(ah, Bl[kt], acc[mt], 0,0,0);
      acc[mt] = __builtin_amdgcn_mfma_f32_16x16x32_f16(ah, Bh[kt], acc[mt], 0,0,0);
    }
  }
  CFENCE();   // all B reads done before in-place writes
#pragma unroll
  for (int mt = 0; mt < MT; ++mt) {
    const f32x4 b4 = *(const f32x4*)&bias[16*mt + 4*g];
    f16x4 vh, vl;
#pragma unroll
    for (int r = 0; r < 4; ++r) {
      const float x = fmaxf(acc[mt][r] + b4[r], 0.0f);
      const f16 h = (f16)x;
      vh[r] = h;
      vl[r] = (f16)(x - (float)h);
    }
    const int wi = p*64 + ((16*mt + 4*g) ^ sw);
    *(f16x4*)&acth[wi] = vh;
    *(f16x4*)&actl[wi] = vl;
  }
  CFENCE();
}

// vOut: MT=4 (64 strike rows), KT=1; accumulates cvv += g*(W*h + b).
__device__ __forceinline__ void mfma_vout(
    const f16* __restrict__ Ah, const f16* __restrict__ Al,
    const f16* acth, const f16* actl, const float* __restrict__ vbo,
    float gg, f32x4 cvv[4], int p, int g, int sw)
{
  const int bi = p*64 + ((8*g) ^ sw);
  const f16x8 Bh = *(const f16x8*)&acth[bi];
  const f16x8 Bl = *(const f16x8*)&actl[bi];
#pragma unroll
  for (int mt = 0; mt < 4; ++mt) {
    f32x4 acc = (f32x4){0.f,0.f,0.f,0.f};
    const int ai = (p + 16*mt)*40 + 8*g;
    const f16x8 ah = *(const f16x8*)&Ah[ai];
    const f16x8 al = *(const f16x8*)&Al[ai];
    acc = __builtin_amdgcn_mfma_f32_16x16x32_f16(al, Bh, acc, 0,0,0);
    acc = __builtin_amdgcn_mfma_f32_16x16x32_f16(ah, Bl, acc, 0,0,0);
    acc = __builtin_amdgcn_mfma_f32_16x16x32_f16(ah, Bh, acc, 0,0,0);
    const f32x4 b4 = *(const f32x4*)&vbo[16*mt + 4*g];
#pragma unroll
    for (int r = 0; r < 4; ++r)
      cvv[mt][r] = fmaf(gg, acc[r] + b4[r], cvv[mt][r]);
  }
}

// diff L1 (2->64 padded): VALU, writes f16 hi/lo act. 16 neurons per lane.
__device__ __forceinline__ void diff_L1(const float* sm, f16* acth, f16* actl,
                                        float tp, float Sp, int p, int g, int sw)
{
  const int j0 = 16*g;
  f16x8 vh0, vh1, vl0, vl1;
#pragma unroll
  for (int c = 0; c < 4; ++c) {
    const f32x4 w0 = *(const f32x4*)&sm[OFF_DW0 + j0 + 4*c];
    const f32x4 w1 = *(const f32x4*)&sm[OFF_DW1 + j0 + 4*c];
    const f32x4 bi = *(const f32x4*)&sm[OFF_DBI + j0 + 4*c];
#pragma unroll
    for (int r = 0; r < 4; ++r) {
      const float x = fmaxf(fmaf(w0[r], tp, fmaf(w1[r], Sp, bi[r])), 0.0f);
      const f16 h = (f16)x;
      const f16 l = (f16)(x - (float)h);
      if (c < 2) { vh0[c*4+r] = h; vl0[c*4+r] = l; }
      else       { vh1[(c-2)*4+r] = h; vl1[(c-2)*4+r] = l; }
    }
  }
  const int wi0 = p*64 + (j0 ^ sw);
  const int wi1 = p*64 + ((j0 + 8) ^ sw);
  *(f16x8*)&acth[wi0] = vh0; *(f16x8*)&acth[wi1] = vh1;
  *(f16x8*)&actl[wi0] = vl0; *(f16x8*)&actl[wi1] = vl1;
  CFENCE();
}

// diff output layer (64->1): exact f32 dot over k-quarter + shfl reduce.
__device__ __forceinline__ float diff_out(const float* sm, const f16* acth,
                                          const f16* actl, int p, int g, int sw)
{
  const int kb = 16*g;
  const f16x8 h0 = *(const f16x8*)&acth[p*64 + (kb ^ sw)];
  const f16x8 h1 = *(const f16x8*)&acth[p*64 + ((kb+8) ^ sw)];
  const f16x8 l0 = *(const f16x8*)&actl[p*64 + (kb ^ sw)];
  const f16x8 l1 = *(const f16x8*)&actl[p*64 + ((kb+8) ^ sw)];
  float s = 0.0f;
#pragma unroll
  for (int e = 0; e < 8; ++e) {
    s = fmaf((float)h0[e] + (float)l0[e], sm[OFF_DWO + kb + e], s);
    s = fmaf((float)h1[e] + (float)l1[e], sm[OFF_DWO + kb + 8 + e], s);
  }
  s += __shfl_xor(s, 16); s += __shfl_xor(s, 32);
  return softplus_f(s + sm[OFF_SC]);
}

// full diff net
__device__ __forceinline__ float diff_chain(const float* sm, const f16* smh,
                                            f16* acth, f16* actl,
                                            float tp, float Sp,
                                            int p, int g, int sw)
{
  diff_L1(sm, acth, actl, tp, Sp, p, g, sw);
  mfma_hidden<4,2,true>(smh + DWH_HI_F,        smh + DWH_LO_F,
                        acth, actl, sm + OFF_DBH,       p, g, sw);
  mfma_hidden<4,2,true>(smh + DWH_HI_F + 4096, smh + DWH_LO_F + 4096,
                        acth, actl, sm + OFF_DBH + 64,  p, g, sw);
  mfma_hidden<4,2,true>(smh + DWH_HI_F + 8192, smh + DWH_LO_F + 8192,
                        acth, actl, sm + OFF_DBH + 128, p, g, sw);
  return diff_out(sm, acth, actl, p, g, sw);
}

__device__ void load_weights(float* sm, f16* smh, int m, int tid,
  const float* dWi, const float* dbi_g, const float* dWh_g, const float* dbh_g,
  const float* dWo_g, const float* dbo_g,
  const float* vWi, const float* vbi_g, const float* vWh_g, const float* vbh_g,
  const float* vWo_g, const float* vbo_g,
  const float* ebi_g, const float* eWh_g, const float* ebh_g,
  const float* eWo_g, const float* ebo_g)
{
  for (int j = tid; j < 64; j += TPB) {
    sm[OFF_DW0+j] = (j<50) ? dWi[m*100 + j]      : 0.0f;
    sm[OFF_DW1+j] = (j<50) ? dWi[m*100 + 50 + j] : 0.0f;
    sm[OFF_DBI+j] = (j<50) ? dbi_g[m*50 + j]     : 0.0f;
    sm[OFF_DWO+j] = (j<50) ? dWo_g[m*50 + j]     : 0.0f;
  }
  for (int idx = tid; idx < 192; idx += TPB) {
    const int l = idx >> 6, j = idx & 63;
    sm[OFF_DBH+idx] = (j<50) ? dbh_g[(m*3+l)*50 + j] : 0.0f;
  }
  for (int j = tid; j < 32; j += TPB) {
    sm[OFF_VW0+j] = (j<30) ? vWi[m*60 + j]      : 0.0f;
    sm[OFF_VW1+j] = (j<30) ? vWi[m*60 + 30 + j] : 0.0f;
    sm[OFF_VBI+j] = (j<30) ? vbi_g[m*30 + j]    : 0.0f;
    sm[OFF_EBI+j] = (j<20) ? ebi_g[m*20 + j]    : 0.0f;
    sm[OFF_EWO+j] = (j<20) ? eWo_g[m*20 + j]    : 0.0f;
  }
  for (int idx = tid; idx < 64; idx += TPB) {
    const int l = idx >> 5, j = idx & 31;
    sm[OFF_VBH+idx] = (j<30) ? vbh_g[(m*2+l)*30 + j] : 0.0f;
    sm[OFF_EBH+idx] = (j<20) ? ebh_g[(m*2+l)*20 + j] : 0.0f;
  }
  for (int j = tid; j < 64; j += TPB)
    sm[OFF_VBO+j] = (j<63) ? vbo_g[m*63 + j] : 0.0f;
  if (tid == 0) { sm[OFF_SC] = dbo_g[m]; sm[OFF_SC+1] = ebo_g[m]; }

  // diff hidden weights -> f16 hi/lo, A[j][k] = W[k][j], swizzled stride-64
  for (int idx = tid; idx < 12288; idx += TPB) {
    const int l = idx >> 12, j = (idx >> 6) & 63, k = idx & 63;
    const float w = (j<50 && k<50) ? dWh_g[((m*3+l)*50 + k)*50 + j] : 0.0f;
    const f16 h = (f16)w;
    const int o = l*4096 + j*64 + (k ^ ((j&7)<<3));
    smh[DWH_HI_F + o] = h;
    smh[DWH_LO_F + o] = (f16)(w - (float)h);
  }
  // vv & ve hidden: A[j][k], stride-40, no swizzle
  for (int idx = tid; idx < 2560; idx += TPB) {
    const int l = idx / 1280, r = idx % 1280, j = r / 40, k = r % 40;
    {
      const float w = (j<30 && k<30) ? vWh_g[((m*2+l)*30 + k)*30 + j] : 0.0f;
      const f16 h = (f16)w;
      smh[VWH_F + l*2560 + j*40 + k]        = h;
      smh[VWH_F + l*2560 + 1280 + j*40 + k] = (f16)(w - (float)h);
    }
    {
      const float w = (j<20 && k<20) ? eWh_g[((m*2+l)*20 + k)*20 + j] : 0.0f;
      const f16 h = (f16)w;
      smh[EWH_F + l*2560 + j*40 + k]        = h;
      smh[EWH_F + l*2560 + 1280 + j*40 + k] = (f16)(w - (float)h);
    }
  }
  // vOut: A[s][k] = vWo[k][s], [64][40]
  for (int idx = tid; idx < 2560; idx += TPB) {
    const int s = idx / 40, k = idx % 40;
    const float w = (s<63 && k<30) ? vWo_g[(m*30 + k)*63 + s] : 0.0f;
    const f16 h = (f16)w;
    smh[VWO_HI_F + idx] = h;
    smh[VWO_LO_F + idx] = (f16)(w - (float)h);
  }
}

extern "C" __global__ void __launch_bounds__(TPB, 2)
sim_kernel(const float* __restrict__ S0g, const float* __restrict__ zg,
           const float* dWi, const float* dbi_g, const float* dWh_g,
           const float* dbh_g, const float* dWo_g, const float* dbo_g,
           const float* vWi, const float* vbi_g, const float* vWh_g,
           const float* vbh_g, const float* vWo_g, const float* vbo_g,
           const float* eWi, const float* ebi_g, const float* eWh_g,
           const float* ebh_g, const float* eWo_g, const float* ebo_g,
           float* __restrict__ out, double* __restrict__ wsd)
{
  extern __shared__ float sm[];
  f16* smh = (f16*)&sm[F16BASE];
  const int tid  = threadIdx.x;
  const int wv   = tid >> 6;          // wave 0..7, owns 16 paths
  const int lane = tid & 63;
  const int p    = lane & 15;         // path within wave (& A-row & D-col)
  const int g    = lane >> 4;         // k-slot / row-quarter group 0..3
  const int sw   = (p & 7) << 3;      // act/weight XOR swizzle
  f16* acth = smh + ACT_F + wv*2048;
  f16* actl = acth + 1024;
  const int P0 = blockIdx.x*128 + wv*16;
  const float S0v = S0g[0];

  // EWI f32 once ([3][92][20])
  for (int idx = tid; idx < 5520; idx += TPB) sm[OFF_EWI + idx] = eWi[idx];

  f32x4 cvv[4];   // strike rows 16mt+4g+r, path p
#pragma unroll
  for (int mt = 0; mt < 4; ++mt) cvv[mt] = (f32x4){0.f,0.f,0.f,0.f};
  float S = S0v, rmax = S0v, cve = 0.0f;

  if (g == 0) out[PATH_OFF + (size_t)(P0 + p) * NGRID + 0] = S0v;
  __syncthreads();   // EWI ready

  // incremental cve-L1 accumulators: path p, rows 8g..8g+7 (j>=20 unused)
  float accCur[8], accN[8], accN2[8];
#pragma unroll
  for (int e = 0; e < 8; ++e) {
    const int r1 = 20 + 8*g + e;     // EWI row 1 (path[0]=S0 term)
    accCur[e] = S0v * sm[OFF_EWI + 0*1840 + r1];
    accN[e]   = S0v * sm[OFF_EWI + 1*1840 + r1];
    accN2[e]  = S0v * sm[OFF_EWI + 2*1840 + r1];
  }

  for (int m = 0; m < 3; ++m) {
    if (m > 0) {
#pragma unroll
      for (int e = 0; e < 8; ++e) { accCur[e] = accN[e]; accN[e] = accN2[e]; }
    }
    __syncthreads();
    load_weights(sm, smh, m, tid, dWi, dbi_g, dWh_g, dbh_g, dWo_g, dbo_g,
                 vWi, vbi_g, vWh_g, vbh_g, vWo_g, vbo_g,
                 ebi_g, eWh_g, ebh_g, eWo_g, ebo_g);
    __syncthreads();

    if (m == 0) {
      const float d0 = diff_chain(sm, smh, acth, actl, 0.0f, S, p, g, sw);
      if (g == 0)
        out[VARP_OFF + (size_t)(P0 + p) * NGRID + 0] = d0 * d0;
      CFENCE();
    }

    for (int it = 1; it <= 30; ++it) {
      const int i = m*30 + it;
      const float ti = 0.01f * (float)i;
      const float tp = 0.01f * (float)(i - 1);
      const float hstep = ti - tp;
      const float sqh = sqrtf(hstep);
      const float disc = expf(-RATEf * tp);
      const float zval = zg[(size_t)(P0 + p) * NSTEPS + (i - 1)];
      const float dWv = sqh * zval;

      // ---------------- diff net (MFMA) ----------------
      const float d = diff_chain(sm, smh, acth, actl, tp, S, p, g, sw);
      const float gg = ((disc * S) * d) * dWv;   // S is old S
      if (g == 0) {
        out[VARP_OFF + (size_t)(P0 + p) * NGRID + i] = d * d;
        if (i == NSTEPS) out[DL_OFF + (P0 + p)] = d;
      }

      // ---------------- vv net ----------------
      { // vL1: 8 neurons per lane (rows 8g.., >=30 auto-zero via pads)
        const int j0 = 8*g;
        f16x8 vh, vl;
#pragma unroll
        for (int c = 0; c < 2; ++c) {
          const f32x4 w0 = *(const f32x4*)&sm[OFF_VW0 + j0 + 4*c];
          const f32x4 w1 = *(const f32x4*)&sm[OFF_VW1 + j0 + 4*c];
          const f32x4 bi = *(const f32x4*)&sm[OFF_VBI + j0 + 4*c];
#pragma unroll
          for (int r = 0; r < 4; ++r) {
            const float x = fmaxf(fmaf(w0[r], tp, fmaf(w1[r], S, bi[r])), 0.0f);
            const f16 h = (f16)x;
            vh[c*4+r] = h;
            vl[c*4+r] = (f16)(x - (float)h);
          }
        }
        const int wi = p*64 + (j0 ^ sw);
        *(f16x8*)&acth[wi] = vh;
        *(f16x8*)&actl[wi] = vl;
        CFENCE();
      }
      mfma_hidden<2,1,false>(smh + VWH_F,        smh + VWH_F + 1280,
                             acth, actl, sm + OFF_VBH,      p, g, sw);
      mfma_hidden<2,1,false>(smh + VWH_F + 2560, smh + VWH_F + 3840,
                             acth, actl, sm + OFF_VBH + 32, p, g, sw);
      mfma_vout(smh + VWO_HI_F, smh + VWO_LO_F, acth, actl,
                sm + OFF_VBO, gg, cvv, p, g, sw);

      // ---------------- ve net ----------------
      { // eL1: rows 8g..8g+7 from incremental accumulators (mask j>=20)
        const int j0 = 8*g;
        const int ewb = OFF_EWI + m*1840;     // row 0 = t weights
        const f32x4 t0 = *(const f32x4*)&sm[ewb + j0];
        const f32x4 t1 = *(const f32x4*)&sm[ewb + j0 + 4];
        const f32x4 b0 = *(const f32x4*)&sm[OFF_EBI + j0];
        const f32x4 b1 = *(const f32x4*)&sm[OFF_EBI + j0 + 4];
        f16x8 vh, vl;
#pragma unroll
        for (int e = 0; e < 8; ++e) {
          const float wt = (e < 4) ? t0[e] : t1[e-4];
          const float bb = (e < 4) ? b0[e] : b1[e-4];
          float x = fmaxf(fmaf(wt, tp, accCur[e] + bb), 0.0f);
          if (j0 + e >= 20) x = 0.0f;
          const f16 h = (f16)x;
          vh[e] = h;
          vl[e] = (f16)(x - (float)h);
        }
        const int wi = p*64 + (j0 ^ sw);
        *(f16x8*)&acth[wi] = vh;
        *(f16x8*)&actl[wi] = vl;
        CFENCE();
      }
      mfma_hidden<2,1,false>(smh + EWH_F,        smh + EWH_F + 1280,
                             acth, actl, sm + OFF_EBH,      p, g, sw);
      mfma_hidden<2,1,false>(smh + EWH_F + 2560, smh + EWH_F + 3840,
                             acth, actl, sm + OFF_EBH + 32, p, g, sw);
      float oute;
      { // eOut: k-quarter 8g..8g+7 (k>=20 zero), shfl reduce
        const int kb = 8*g;
        const f16x8 h = *(const f16x8*)&acth[p*64 + (kb ^ sw)];
        const f16x8 l = *(const f16x8*)&actl[p*64 + (kb ^ sw)];
        float s_ = 0.0f;
#pragma unroll
        for (int e = 0; e < 8; ++e)
          s_ = fmaf((float)h[e] + (float)l[e], sm[OFF_EWO + kb + e], s_);
        s_ += __shfl_xor(s_, 16); s_ += __shfl_xor(s_, 32);
        oute = s_ + sm[OFF_SC + 1];
      }
      cve = fmaf(gg, oute, cve);

      // ---------------- state update ----------------
      const float Sold = S;
      const float t1_ = (RATEf*Sold*hstep) / (1.0f + (RATEf*Sold)*sqh);
      const float t2_ = ((Sold*d)*dWv)     / (1.0f + (Sold*d)*sqh);
      const float Snew = (Sold + t1_) + t2_;
      S = Snew;
      rmax = fmaxf(rmax, Snew);
      if (g == 0)
        out[PATH_OFF + (size_t)(P0 + p) * NGRID + i] = Snew;
      { // incremental cve-L1 update with EWI row (1+i)
        const int ro = (1 + i)*20 + 8*g;
        const int bm = m*1840;
        const int bn = (m < 2 ? m + 1 : 2) * 1840;
        const f32x4 a0 = *(const f32x4*)&sm[OFF_EWI + bm + ro];
        const f32x4 a1 = *(const f32x4*)&sm[OFF_EWI + bm + ro + 4];
        const f32x4 c0 = *(const f32x4*)&sm[OFF_EWI + bn + ro];
        const f32x4 c1 = *(const f32x4*)&sm[OFF_EWI + bn + ro + 4];
        const f32x4 d0_ = *(const f32x4*)&sm[OFF_EWI + 3680 + ro];
        const f32x4 d1_ = *(const f32x4*)&sm[OFF_EWI + 3680 + ro + 4];
#pragma unroll
        for (int e = 0; e < 8; ++e) {
          accCur[e] = fmaf(Snew, (e<4) ? a0[e] : a1[e-4], accCur[e]);
          accN[e]   = fmaf(Snew, (e<4) ? c0[e] : c1[e-4], accN[e]);
          accN2[e]  = fmaf(Snew, (e<4) ? d0_[e] : d1_[e-4], accN2[e]);
        }
      }
      CFENCE();
    } // steps

    // ---------------- period-end price partials ----------------
    {
      const float discm = expf(-RATEf * (0.01f * (float)(30*(m+1))));
      double* ps = (double*)&sm[OFF_PSUM];
#pragma unroll
      for (int mt = 0; mt < 4; ++mt) {
#pragma unroll
        for (int r = 0; r < 4; ++r) {
          const int s = 16*mt + 4*g + r;
          const bool act = (s >= 21*m) && (s < 21*m + 21);
          double s1 = 0.0, s2 = 0.0;
          if (act) {
            const float Kst = 0.8f + 0.02f * (float)(s - 21*m);
            const float pr_ = discm * fmaxf(S - Kst, 0.0f) - cvv[mt][r];
            s1 = (double)pr_;
            s2 = (double)pr_ * (double)pr_;
          }
          s1 += __shfl_xor(s1, 1); s1 += __shfl_xor(s1, 2);
          s1 += __shfl_xor(s1, 4); s1 += __shfl_xor(s1, 8);
          s2 += __shfl_xor(s2, 1); s2 += __shfl_xor(s2, 2);
          s2 += __shfl_xor(s2, 4); s2 += __shfl_xor(s2, 8);
          if (act && p == 0) {
            const int sI = s - 21*m;
            ps[wv*42 + sI*2 + 0] = s1;
            ps[wv*42 + sI*2 + 1] = s2;
          }
        }
      }
    }
    __syncthreads();
    if (tid < 21) {
      double* ps = (double*)&sm[OFF_PSUM];
      double a = 0.0, b = 0.0;
      for (int w = 0; w < 8; ++w) { a += ps[w*42 + tid*2]; b += ps[w*42 + tid*2 + 1]; }
      wsd[(size_t)blockIdx.x*WS_STRIDE + (m*21+tid)*2 + 0] = a;
      wsd[(size_t)blockIdx.x*WS_STRIDE + (m*21+tid)*2 + 1] = b;
    }
  } // periods

  // ---------------- exotic outputs & partials ----------------
  const float discT = expf(-RATEf * (0.01f * 90.0f));
  const float e  = discT * (rmax - S);
  const float ep = e - cve;
  if (g == 0) out[EP_OFF + (P0 + p)] = ep;
  double de  = (g == 0) ? (double)e  : 0.0;
  double dp  = (g == 0) ? (double)ep : 0.0;
  double dp2 = (g == 0) ? (double)ep * (double)ep : 0.0;
#pragma unroll
  for (int msk = 1; msk <= 32; msk <<= 1) {
    de  += __shfl_xor(de,  msk);
    dp  += __shfl_xor(dp,  msk);
    dp2 += __shfl_xor(dp2, msk);
  }
  {
    double* es = (double*)&sm[OFF_ESUM];
    if (lane == 0) { es[wv*4+0] = de; es[wv*4+1] = dp; es[wv*4+2] = dp2; }
  }
  __syncthreads();
  if (tid == 0) {
    double* es = (double*)&sm[OFF_ESUM];
    double a = 0, b = 0, c = 0;
    for (int w = 0; w < 8; ++w) { a += es[w*4]; b += es[w*4+1]; c += es[w*4+2]; }
    wsd[(size_t)blockIdx.x*WS_STRIDE + 126] = a;
    wsd[(size_t)blockIdx.x*WS_STRIDE + 127] = b;
    wsd[(size_t)blockIdx.x*WS_STRIDE + 128] = c;
  }
}

extern "C" __global__ void finalize_kernel(double* __restrict__ wsd,
                                           float* __restrict__ out)
{
  const int t = threadIdx.x;
  if (t < 63) {
    double a = 0.0, b = 0.0;
    for (int blk = 0; blk < NBLK; ++blk) {
      a += wsd[(size_t)blk*WS_STRIDE + t*2 + 0];
      b += wsd[(size_t)blk*WS_STRIDE + t*2 + 1];
    }
    const double mean = a / (double)MC;
    const double var  = (b - a*a/(double)MC) / (double)(MC - 1);
    out[PV_OFF + t] = (float)mean;
    out[VV_OFF + t] = (float)var;
  } else if (t == 64) {
    double a = 0.0;
    for (int blk = 0; blk < NBLK; ++blk) a += wsd[(size_t)blk*WS_STRIDE + 126];
    wsd[MEANE_SLOT] = a / (double)MC;
  } else if (t == 65) {
    double a = 0.0, c = 0.0;
    for (int blk = 0; blk < NBLK; ++blk) {
      a += wsd[(size_t)blk*WS_STRIDE + 127];
      c += wsd[(size_t)blk*WS_STRIDE + 128];
    }
    out[MEAN_OFF] = (float)(a / (double)MC);
    out[VAR_OFF]  = (float)((c - a*a/(double)MC) / (double)(MC - 1));
  }
}

extern "C" __global__ void error_kernel(const double* __restrict__ wsd,
                                        float* __restrict__ out)
{
  const int pth = blockIdx.x * 256 + threadIdx.x;
  if (pth < MC) {
    const float meanE = (float)wsd[MEANE_SLOT];
    out[ERR_OFF + pth] = out[EP_OFF + pth] - meanE;
  }
}

extern "C" void kernel_launch(void* const* d_in, const int* in_sizes, int n_in,
                              void* d_out, int out_size, void* d_ws, size_t ws_size,
                              hipStream_t stream)
{
  (void)in_sizes; (void)n_in; (void)out_size; (void)ws_size;
  const float* S0g  = (const float*)d_in[0];
  const float* zg   = (const float*)d_in[1];
  // d_in[2..4] = MC_samples / ind_T / period_length (fixed constants)
  const float* dWi  = (const float*)d_in[5];
  const float* dbi  = (const float*)d_in[6];
  const float* dWh  = (const float*)d_in[7];
  const float* dbh  = (const float*)d_in[8];
  const float* dWo  = (const float*)d_in[9];
  const float* dbo  = (const float*)d_in[10];
  const float* vWi  = (const float*)d_in[11];
  const float* vbi  = (const float*)d_in[12];
  const float* vWh  = (const float*)d_in[13];
  const float* vbh  = (const float*)d_in[14];
  const float* vWo  = (const float*)d_in[15];
  const float* vbo  = (const float*)d_in[16];
  const float* eWi  = (const float*)d_in[17];
  const float* ebi  = (const float*)d_in[18];
  const float* eWh  = (const float*)d_in[19];
  const float* ebh  = (const float*)d_in[20];
  const float* eWo  = (const float*)d_in[21];
  const float* ebo  = (const float*)d_in[22];
  float* out  = (float*)d_out;
  double* wsd = (double*)d_ws;

  hipFuncSetAttribute(reinterpret_cast<const void*>(sim_kernel),
                      hipFuncAttributeMaxDynamicSharedMemorySize, SMEM_BYTES);

  sim_kernel<<<NBLK, TPB, SMEM_BYTES, stream>>>(
      S0g, zg, dWi, dbi, dWh, dbh, dWo, dbo,
      vWi, vbi, vWh, vbh, vWo, vbo,
      eWi, ebi, eWh, ebh, eWo, ebo, out, wsd);
  finalize_kernel<<<1, 128, 0, stream>>>(wsd, out);
  error_kernel<<<MC/256, 256, 0, stream>>>(wsd, out);
}

// Round 7
// 584.581 us; speedup vs baseline: 3.0927x; 1.1873x over previous
//
#include <hip/hip_runtime.h>
#include <math.h>

// ---------------------------------------------------------------------------
// Net_LV Monte-Carlo local-vol simulation, MI355X (gfx950)  — MFMA version 2
// 256 blocks x 512 threads. Each WAVE independently owns 16 paths end-to-end;
// zero block barriers in the step loop.
// diff net: v_mfma_f32_16x16x32_f16 with 2-term f16 hi/lo splits (3 MFMA/tile).
// vv/ve/vOut nets: single-f16 (1 MFMA/tile), own act buffers, computed BEFORE
// the diff chain (independent of d) for cross-stream ILP.
// ---------------------------------------------------------------------------

#define TPB 512
#define NBLK 256
#define MC 32768
#define NSTEPS 90
#define NGRID 91
#define RATEf 0.025f

typedef _Float16 f16;
typedef f16 f16x8 __attribute__((ext_vector_type(8)));
typedef f16 f16x4 __attribute__((ext_vector_type(4)));
typedef float f32x4 __attribute__((ext_vector_type(4)));

#define CFENCE() asm volatile("" ::: "memory")

__device__ __forceinline__ float fast_rcp(float x) {
  float r; asm("v_rcp_f32 %0, %1" : "=v"(r) : "v"(x)); return r;
}

// ---- d_out offsets (float elements), in reference return order ----
#define PATH_OFF   0
#define VARP_OFF   (MC*NGRID)
#define DL_OFF     (2*MC*NGRID)
#define PV_OFF     (2*MC*NGRID + MC)
#define VV_OFF     (PV_OFF + 63)
#define EP_OFF     (VV_OFF + 63)
#define MEAN_OFF   (EP_OFF + MC)
#define VAR_OFF    (MEAN_OFF + 1)
#define ERR_OFF    (VAR_OFF + 1)

// ---- workspace (doubles) ----
#define WS_STRIDE  132
#define MEANE_SLOT (NBLK*WS_STRIDE)

// ---- LDS f32 offsets (dwords) ----
enum : int {
  OFF_DW0 = 0,     // diff Wi t-row, padded 64
  OFF_DW1 = 64,
  OFF_DBI = 128,
  OFF_DWO = 192,
  OFF_DBH = 256,   // 3*64
  OFF_VW0 = 448,   // padded 32
  OFF_VW1 = 480,
  OFF_VBI = 512,
  OFF_VBH = 544,   // 2*32
  OFF_VBO = 608,   // 64
  OFF_EBI = 672,   // 32
  OFF_EBH = 704,   // 2*32
  OFF_EWO = 768,   // 32
  OFF_SC  = 800,   // [0]=dbo, [1]=ebo  (pad to 804)
  OFF_EWI = 804,   // f32 [3][92][20] = 5520 (+32 pad) = 5552
  OFF_PSUM= 6356,  // 8 waves * 42 doubles = 672 dw
  OFF_ESUM= 7028,  // 8 waves * 4 doubles = 64 dw
  F16BASE = 7092
};
// ---- f16 offsets (units of f16, relative to smh) ----
enum : int {
  DWH_HI_F = 0,        // 3 * [64][64] swizzled (hi/lo 2-term)
  DWH_LO_F = 12288,
  VWH_F    = 24576,    // 2 * [32][40] single f16
  EWH_F    = 27136,    // 2 * [32][40]
  VWO_F    = 29696,    // [64][40]
  ACT_F    = 32256     // per wave: diff hi 1024 | diff lo 1024 | vv 640 | ve 640
};
#define SMEM_DW   36532
#define SMEM_BYTES (SMEM_DW*4)

__device__ __forceinline__ float softplus_f(float x) {
  return fmaxf(x, 0.0f) + log1pf(expf(-fabsf(x)));
}

// ---- diff net pieces (2-term hi/lo, unchanged from R6) ----
template<int MT, int KT>
__device__ __forceinline__ void mfma_hidden_d(
    const f16* __restrict__ Ah, const f16* __restrict__ Al,
    f16* acth, f16* actl, const float* __restrict__ bias,
    int p, int g, int sw)
{
  f16x8 Bh[KT], Bl[KT];
#pragma unroll
  for (int kt = 0; kt < KT; ++kt) {
    const int bi = p*64 + ((32*kt + 8*g) ^ sw);
    Bh[kt] = *(const f16x8*)&acth[bi];
    Bl[kt] = *(const f16x8*)&actl[bi];
  }
  f32x4 acc[MT];
#pragma unroll
  for (int mt = 0; mt < MT; ++mt) acc[mt] = (f32x4){0.f,0.f,0.f,0.f};
#pragma unroll
  for (int mt = 0; mt < MT; ++mt) {
#pragma unroll
    for (int kt = 0; kt < KT; ++kt) {
      const int ai = (p + 16*mt)*64 + ((32*kt + 8*g) ^ sw);
      const f16x8 ah = *(const f16x8*)&Ah[ai];
      const f16x8 al = *(const f16x8*)&Al[ai];
      acc[mt] = __builtin_amdgcn_mfma_f32_16x16x32_f16(al, Bh[kt], acc[mt], 0,0,0);
      acc[mt] = __builtin_amdgcn_mfma_f32_16x16x32_f16(ah, Bl[kt], acc[mt], 0,0,0);
      acc[mt] = __builtin_amdgcn_mfma_f32_16x16x32_f16(ah, Bh[kt], acc[mt], 0,0,0);
    }
  }
  CFENCE();   // all B reads done before in-place writes
#pragma unroll
  for (int mt = 0; mt < MT; ++mt) {
    const f32x4 b4 = *(const f32x4*)&bias[16*mt + 4*g];
    f16x4 vh, vl;
#pragma unroll
    for (int r = 0; r < 4; ++r) {
      const float x = fmaxf(acc[mt][r] + b4[r], 0.0f);
      const f16 h = (f16)x;
      vh[r] = h;
      vl[r] = (f16)(x - (float)h);
    }
    const int wi = p*64 + ((16*mt + 4*g) ^ sw);
    *(f16x4*)&acth[wi] = vh;
    *(f16x4*)&actl[wi] = vl;
  }
  CFENCE();
}

__device__ __forceinline__ void diff_L1(const float* sm, f16* acth, f16* actl,
                                        float tp, float Sp, int p, int g, int sw)
{
  const int j0 = 16*g;
  f16x8 vh0, vh1, vl0, vl1;
#pragma unroll
  for (int c = 0; c < 4; ++c) {
    const f32x4 w0 = *(const f32x4*)&sm[OFF_DW0 + j0 + 4*c];
    const f32x4 w1 = *(const f32x4*)&sm[OFF_DW1 + j0 + 4*c];
    const f32x4 bi = *(const f32x4*)&sm[OFF_DBI + j0 + 4*c];
#pragma unroll
    for (int r = 0; r < 4; ++r) {
      const float x = fmaxf(fmaf(w0[r], tp, fmaf(w1[r], Sp, bi[r])), 0.0f);
      const f16 h = (f16)x;
      const f16 l = (f16)(x - (float)h);
      if (c < 2) { vh0[c*4+r] = h; vl0[c*4+r] = l; }
      else       { vh1[(c-2)*4+r] = h; vl1[(c-2)*4+r] = l; }
    }
  }
  const int wi0 = p*64 + (j0 ^ sw);
  const int wi1 = p*64 + ((j0 + 8) ^ sw);
  *(f16x8*)&acth[wi0] = vh0; *(f16x8*)&acth[wi1] = vh1;
  *(f16x8*)&actl[wi0] = vl0; *(f16x8*)&actl[wi1] = vl1;
  CFENCE();
}

__device__ __forceinline__ float diff_out(const float* sm, const f16* acth,
                                          const f16* actl, int p, int g, int sw)
{
  const int kb = 16*g;
  const f16x8 h0 = *(const f16x8*)&acth[p*64 + (kb ^ sw)];
  const f16x8 h1 = *(const f16x8*)&acth[p*64 + ((kb+8) ^ sw)];
  const f16x8 l0 = *(const f16x8*)&actl[p*64 + (kb ^ sw)];
  const f16x8 l1 = *(const f16x8*)&actl[p*64 + ((kb+8) ^ sw)];
  float s = 0.0f;
#pragma unroll
  for (int e = 0; e < 8; ++e) {
    s = fmaf((float)h0[e] + (float)l0[e], sm[OFF_DWO + kb + e], s);
    s = fmaf((float)h1[e] + (float)l1[e], sm[OFF_DWO + kb + 8 + e], s);
  }
  s += __shfl_xor(s, 16); s += __shfl_xor(s, 32);
  return softplus_f(s + sm[OFF_SC]);
}

__device__ __forceinline__ float diff_chain(const float* sm, const f16* smh,
                                            f16* acth, f16* actl,
                                            float tp, float Sp,
                                            int p, int g, int sw)
{
  diff_L1(sm, acth, actl, tp, Sp, p, g, sw);
  mfma_hidden_d<4,2>(smh + DWH_HI_F,        smh + DWH_LO_F,
                     acth, actl, sm + OFF_DBH,       p, g, sw);
  mfma_hidden_d<4,2>(smh + DWH_HI_F + 4096, smh + DWH_LO_F + 4096,
                     acth, actl, sm + OFF_DBH + 64,  p, g, sw);
  mfma_hidden_d<4,2>(smh + DWH_HI_F + 8192, smh + DWH_LO_F + 8192,
                     acth, actl, sm + OFF_DBH + 128, p, g, sw);
  return diff_out(sm, acth, actl, p, g, sw);
}

// ---- paired small-net hidden layer (vv & ve together, single f16) ----
__device__ __forceinline__ void small_pair(
    const f16* __restrict__ Av, const f16* __restrict__ Ae,
    f16* vvact, f16* veact,
    const float* __restrict__ vb, const float* __restrict__ eb,
    int p, int g)
{
  const int bi = p*40 + 8*g;
  const f16x8 Bv = *(const f16x8*)&vvact[bi];
  const f16x8 Be = *(const f16x8*)&veact[bi];
  f32x4 av[2], ae[2];
#pragma unroll
  for (int mt = 0; mt < 2; ++mt) {
    const int ai = (p + 16*mt)*40 + 8*g;
    const f16x8 wv = *(const f16x8*)&Av[ai];
    const f16x8 we = *(const f16x8*)&Ae[ai];
    av[mt] = __builtin_amdgcn_mfma_f32_16x16x32_f16(wv, Bv,
             (f32x4){0.f,0.f,0.f,0.f}, 0,0,0);
    ae[mt] = __builtin_amdgcn_mfma_f32_16x16x32_f16(we, Be,
             (f32x4){0.f,0.f,0.f,0.f}, 0,0,0);
  }
  CFENCE();
#pragma unroll
  for (int mt = 0; mt < 2; ++mt) {
    const f32x4 vb4 = *(const f32x4*)&vb[16*mt + 4*g];
    const f32x4 eb4 = *(const f32x4*)&eb[16*mt + 4*g];
    f16x4 xv, xe;
#pragma unroll
    for (int r = 0; r < 4; ++r) {
      xv[r] = (f16)fmaxf(av[mt][r] + vb4[r], 0.0f);
      xe[r] = (f16)fmaxf(ae[mt][r] + eb4[r], 0.0f);
    }
    const int wi = p*40 + 16*mt + 4*g;
    *(f16x4*)&vvact[wi] = xv;
    *(f16x4*)&veact[wi] = xe;
  }
  CFENCE();
}

__device__ void load_weights(float* sm, f16* smh, int m, int tid,
  const float* dWi, const float* dbi_g, const float* dWh_g, const float* dbh_g,
  const float* dWo_g, const float* dbo_g,
  const float* vWi, const float* vbi_g, const float* vWh_g, const float* vbh_g,
  const float* vWo_g, const float* vbo_g,
  const float* ebi_g, const float* eWh_g, const float* ebh_g,
  const float* eWo_g, const float* ebo_g)
{
  for (int j = tid; j < 64; j += TPB) {
    sm[OFF_DW0+j] = (j<50) ? dWi[m*100 + j]      : 0.0f;
    sm[OFF_DW1+j] = (j<50) ? dWi[m*100 + 50 + j] : 0.0f;
    sm[OFF_DBI+j] = (j<50) ? dbi_g[m*50 + j]     : 0.0f;
    sm[OFF_DWO+j] = (j<50) ? dWo_g[m*50 + j]     : 0.0f;
  }
  for (int idx = tid; idx < 192; idx += TPB) {
    const int l = idx >> 6, j = idx & 63;
    sm[OFF_DBH+idx] = (j<50) ? dbh_g[(m*3+l)*50 + j] : 0.0f;
  }
  for (int j = tid; j < 32; j += TPB) {
    sm[OFF_VW0+j] = (j<30) ? vWi[m*60 + j]      : 0.0f;
    sm[OFF_VW1+j] = (j<30) ? vWi[m*60 + 30 + j] : 0.0f;
    sm[OFF_VBI+j] = (j<30) ? vbi_g[m*30 + j]    : 0.0f;
    sm[OFF_EBI+j] = (j<20) ? ebi_g[m*20 + j]    : 0.0f;
    sm[OFF_EWO+j] = (j<20) ? eWo_g[m*20 + j]    : 0.0f;
  }
  for (int idx = tid; idx < 64; idx += TPB) {
    const int l = idx >> 5, j = idx & 31;
    sm[OFF_VBH+idx] = (j<30) ? vbh_g[(m*2+l)*30 + j] : 0.0f;
    sm[OFF_EBH+idx] = (j<20) ? ebh_g[(m*2+l)*20 + j] : 0.0f;
  }
  for (int j = tid; j < 64; j += TPB)
    sm[OFF_VBO+j] = (j<63) ? vbo_g[m*63 + j] : 0.0f;
  if (tid == 0) { sm[OFF_SC] = dbo_g[m]; sm[OFF_SC+1] = ebo_g[m]; }

  // diff hidden weights -> f16 hi/lo, A[j][k] = W[k][j], swizzled stride-64
  for (int idx = tid; idx < 12288; idx += TPB) {
    const int l = idx >> 12, j = (idx >> 6) & 63, k = idx & 63;
    const float w = (j<50 && k<50) ? dWh_g[((m*3+l)*50 + k)*50 + j] : 0.0f;
    const f16 h = (f16)w;
    const int o = l*4096 + j*64 + (k ^ ((j&7)<<3));
    smh[DWH_HI_F + o] = h;
    smh[DWH_LO_F + o] = (f16)(w - (float)h);
  }
  // vv & ve hidden: A[j][k] single f16, [32][40]
  for (int idx = tid; idx < 2560; idx += TPB) {
    const int l = idx / 1280, r = idx % 1280, j = r / 40, k = r % 40;
    smh[VWH_F + idx] = (f16)((j<30 && k<30) ? vWh_g[((m*2+l)*30 + k)*30 + j] : 0.0f);
    smh[EWH_F + idx] = (f16)((j<20 && k<20) ? eWh_g[((m*2+l)*20 + k)*20 + j] : 0.0f);
  }
  // vOut: A[s][k] = vWo[k][s], [64][40] single f16
  for (int idx = tid; idx < 2560; idx += TPB) {
    const int s = idx / 40, k = idx % 40;
    smh[VWO_F + idx] = (f16)((s<63 && k<30) ? vWo_g[(m*30 + k)*63 + s] : 0.0f);
  }
}

extern "C" __global__ void __launch_bounds__(TPB, 2)
sim_kernel(const float* __restrict__ S0g, const float* __restrict__ zg,
           const float* dWi, const float* dbi_g, const float* dWh_g,
           const float* dbh_g, const float* dWo_g, const float* dbo_g,
           const float* vWi, const float* vbi_g, const float* vWh_g,
           const float* vbh_g, const float* vWo_g, const float* vbo_g,
           const float* eWi, const float* ebi_g, const float* eWh_g,
           const float* ebh_g, const float* eWo_g, const float* ebo_g,
           float* __restrict__ out, double* __restrict__ wsd)
{
  extern __shared__ float sm[];
  f16* smh = (f16*)&sm[F16BASE];
  const int tid  = threadIdx.x;
  const int wv   = tid >> 6;          // wave 0..7, owns 16 paths
  const int lane = tid & 63;
  const int p    = lane & 15;         // path within wave
  const int g    = lane >> 4;         // k-slot / row-quarter group 0..3
  const int sw   = (p & 7) << 3;      // diff act/weight XOR swizzle
  f16* acth  = smh + ACT_F + wv*3328;
  f16* actl  = acth + 1024;
  f16* vvact = acth + 2048;           // [16][40]
  f16* veact = acth + 2688;           // [16][40]
  const int P0 = blockIdx.x*128 + wv*16;
  const float S0v = S0g[0];

  // EWI f32 once ([3][92][20])
  for (int idx = tid; idx < 5520; idx += TPB) sm[OFF_EWI + idx] = eWi[idx];

  f32x4 cvv[4];   // strike rows 16mt+4g+r, path p
#pragma unroll
  for (int mt = 0; mt < 4; ++mt) cvv[mt] = (f32x4){0.f,0.f,0.f,0.f};
  float S = S0v, rmax = S0v, cve = 0.0f;

  if (g == 0) out[PATH_OFF + (size_t)(P0 + p) * NGRID + 0] = S0v;
  __syncthreads();   // EWI ready

  // incremental cve-L1 accumulators: path p, rows 8g..8g+7 (j>=20 unused)
  float accCur[8], accN[8], accN2[8];
#pragma unroll
  for (int e = 0; e < 8; ++e) {
    const int r1 = 20 + 8*g + e;     // EWI row 1 (path[0]=S0 term)
    accCur[e] = S0v * sm[OFF_EWI + 0*1840 + r1];
    accN[e]   = S0v * sm[OFF_EWI + 1*1840 + r1];
    accN2[e]  = S0v * sm[OFF_EWI + 2*1840 + r1];
  }

  for (int m = 0; m < 3; ++m) {
    if (m > 0) {
#pragma unroll
      for (int e = 0; e < 8; ++e) { accCur[e] = accN[e]; accN[e] = accN2[e]; }
    }
    __syncthreads();
    load_weights(sm, smh, m, tid, dWi, dbi_g, dWh_g, dbh_g, dWo_g, dbo_g,
                 vWi, vbi_g, vWh_g, vbh_g, vWo_g, vbo_g,
                 ebi_g, eWh_g, ebh_g, eWo_g, ebo_g);
    __syncthreads();

    if (m == 0) {
      const float d0 = diff_chain(sm, smh, acth, actl, 0.0f, S, p, g, sw);
      if (g == 0)
        out[VARP_OFF + (size_t)(P0 + p) * NGRID + 0] = d0 * d0;
      CFENCE();
    }

    for (int it = 1; it <= 30; ++it) {
      const int i = m*30 + it;
      const float ti = 0.01f * (float)i;
      const float tp = 0.01f * (float)(i - 1);
      const float hstep = ti - tp;
      const float sqh = sqrtf(hstep);
      const float disc = expf(-RATEf * tp);
      const float zval = zg[(size_t)(P0 + p) * NSTEPS + (i - 1)];
      const float dWv = sqh * zval;

      // ---------------- small-net L1s (depend only on S_old / accCur) ----
      { // vL1: rows 8g..8g+7 (pads >=30 auto-zero)
        const int j0 = 8*g;
        f16x8 vh;
#pragma unroll
        for (int c = 0; c < 2; ++c) {
          const f32x4 w0 = *(const f32x4*)&sm[OFF_VW0 + j0 + 4*c];
          const f32x4 w1 = *(const f32x4*)&sm[OFF_VW1 + j0 + 4*c];
          const f32x4 bi = *(const f32x4*)&sm[OFF_VBI + j0 + 4*c];
#pragma unroll
          for (int r = 0; r < 4; ++r)
            vh[c*4+r] = (f16)fmaxf(fmaf(w0[r], tp, fmaf(w1[r], S, bi[r])), 0.0f);
        }
        *(f16x8*)&vvact[p*40 + j0] = vh;
      }
      { // eL1: rows 8g..8g+7 from incremental accumulators (mask j>=20)
        const int j0 = 8*g;
        const int ewb = OFF_EWI + m*1840;     // row 0 = t weights
        const f32x4 t0 = *(const f32x4*)&sm[ewb + j0];
        const f32x4 t1 = *(const f32x4*)&sm[ewb + j0 + 4];
        const f32x4 b0 = *(const f32x4*)&sm[OFF_EBI + j0];
        const f32x4 b1 = *(const f32x4*)&sm[OFF_EBI + j0 + 4];
        f16x8 vh;
#pragma unroll
        for (int e = 0; e < 8; ++e) {
          const float wt = (e < 4) ? t0[e] : t1[e-4];
          const float bb = (e < 4) ? b0[e] : b1[e-4];
          float x = fmaxf(fmaf(wt, tp, accCur[e] + bb), 0.0f);
          if (j0 + e >= 20) x = 0.0f;
          vh[e] = (f16)x;
        }
        *(f16x8*)&veact[p*40 + j0] = vh;
      }
      CFENCE();
      // ---------------- small-net hidden layers (4 indep MFMAs each) ----
      small_pair(smh + VWH_F,        smh + EWH_F,
                 vvact, veact, sm + OFF_VBH,      sm + OFF_EBH,      p, g);
      small_pair(smh + VWH_F + 1280, smh + EWH_F + 1280,
                 vvact, veact, sm + OFF_VBH + 32, sm + OFF_EBH + 32, p, g);

      // ---------------- diff net (MFMA hi/lo 2-term) ----------------
      const float d = diff_chain(sm, smh, acth, actl, tp, S, p, g, sw);
      const float gg = ((disc * S) * d) * dWv;   // S is old S
      if (g == 0) {
        out[VARP_OFF + (size_t)(P0 + p) * NGRID + i] = d * d;
        if (i == NSTEPS) out[DL_OFF + (P0 + p)] = d;
      }

      // ---------------- vOut (single f16) + cvv accumulate ----------------
      {
        const f16x8 Bv = *(const f16x8*)&vvact[p*40 + 8*g];
#pragma unroll
        for (int mt = 0; mt < 4; ++mt) {
          const f16x8 wv = *(const f16x8*)&smh[VWO_F + (p + 16*mt)*40 + 8*g];
          const f32x4 acc = __builtin_amdgcn_mfma_f32_16x16x32_f16(
              wv, Bv, (f32x4){0.f,0.f,0.f,0.f}, 0,0,0);
          const f32x4 b4 = *(const f32x4*)&sm[OFF_VBO + 16*mt + 4*g];
#pragma unroll
          for (int r = 0; r < 4; ++r)
            cvv[mt][r] = fmaf(gg, acc[r] + b4[r], cvv[mt][r]);
        }
      }
      // ---------------- eOut + cve ----------------
      {
        const int kb = 8*g;
        const f16x8 h = *(const f16x8*)&veact[p*40 + kb];
        float s_ = 0.0f;
#pragma unroll
        for (int e = 0; e < 8; ++e)
          s_ = fmaf((float)h[e], sm[OFF_EWO + kb + e], s_);
        s_ += __shfl_xor(s_, 16); s_ += __shfl_xor(s_, 32);
        cve = fmaf(gg, s_ + sm[OFF_SC + 1], cve);
      }

      // ---------------- state update ----------------
      const float Sold = S;
      const float t1_ = (RATEf*Sold*hstep) * fast_rcp(1.0f + (RATEf*Sold)*sqh);
      const float t2_ = ((Sold*d)*dWv)     * fast_rcp(1.0f + (Sold*d)*sqh);
      const float Snew = (Sold + t1_) + t2_;
      S = Snew;
      rmax = fmaxf(rmax, Snew);
      if (g == 0)
        out[PATH_OFF + (size_t)(P0 + p) * NGRID + i] = Snew;
      { // incremental cve-L1 update with EWI row (1+i)
        const int ro = (1 + i)*20 + 8*g;
        const int bm = m*1840;
        const int bn = (m < 2 ? m + 1 : 2) * 1840;
        const f32x4 a0 = *(const f32x4*)&sm[OFF_EWI + bm + ro];
        const f32x4 a1 = *(const f32x4*)&sm[OFF_EWI + bm + ro + 4];
        const f32x4 c0 = *(const f32x4*)&sm[OFF_EWI + bn + ro];
        const f32x4 c1 = *(const f32x4*)&sm[OFF_EWI + bn + ro + 4];
        const f32x4 d0_ = *(const f32x4*)&sm[OFF_EWI + 3680 + ro];
        const f32x4 d1_ = *(const f32x4*)&sm[OFF_EWI + 3680 + ro + 4];
#pragma unroll
        for (int e = 0; e < 8; ++e) {
          accCur[e] = fmaf(Snew, (e<4) ? a0[e] : a1[e-4], accCur[e]);
          accN[e]   = fmaf(Snew, (e<4) ? c0[e] : c1[e-4], accN[e]);
          accN2[e]  = fmaf(Snew, (e<4) ? d0_[e] : d1_[e-4], accN2[e]);
        }
      }
      CFENCE();
    } // steps

    // ---------------- period-end price partials ----------------
    {
      const float discm = expf(-RATEf * (0.01f * (float)(30*(m+1))));
      double* ps = (double*)&sm[OFF_PSUM];
#pragma unroll
      for (int mt = 0; mt < 4; ++mt) {
#pragma unroll
        for (int r = 0; r < 4; ++r) {
          const int s = 16*mt + 4*g + r;
          const bool act = (s >= 21*m) && (s < 21*m + 21);
          double s1 = 0.0, s2 = 0.0;
          if (act) {
            const float Kst = 0.8f + 0.02f * (float)(s - 21*m);
            const float pr_ = discm * fmaxf(S - Kst, 0.0f) - cvv[mt][r];
            s1 = (double)pr_;
            s2 = (double)pr_ * (double)pr_;
          }
          s1 += __shfl_xor(s1, 1); s1 += __shfl_xor(s1, 2);
          s1 += __shfl_xor(s1, 4); s1 += __shfl_xor(s1, 8);
          s2 += __shfl_xor(s2, 1); s2 += __shfl_xor(s2, 2);
          s2 += __shfl_xor(s2, 4); s2 += __shfl_xor(s2, 8);
          if (act && p == 0) {
            const int sI = s - 21*m;
            ps[wv*42 + sI*2 + 0] = s1;
            ps[wv*42 + sI*2 + 1] = s2;
          }
        }
      }
    }
    __syncthreads();
    if (tid < 21) {
      double* ps = (double*)&sm[OFF_PSUM];
      double a = 0.0, b = 0.0;
      for (int w = 0; w < 8; ++w) { a += ps[w*42 + tid*2]; b += ps[w*42 + tid*2 + 1]; }
      wsd[(size_t)blockIdx.x*WS_STRIDE + (m*21+tid)*2 + 0] = a;
      wsd[(size_t)blockIdx.x*WS_STRIDE + (m*21+tid)*2 + 1] = b;
    }
  } // periods

  // ---------------- exotic outputs & partials ----------------
  const float discT = expf(-RATEf * (0.01f * 90.0f));
  const float e  = discT * (rmax - S);
  const float ep = e - cve;
  if (g == 0) out[EP_OFF + (P0 + p)] = ep;
  double de  = (g == 0) ? (double)e  : 0.0;
  double dp  = (g == 0) ? (double)ep : 0.0;
  double dp2 = (g == 0) ? (double)ep * (double)ep : 0.0;
#pragma unroll
  for (int msk = 1; msk <= 32; msk <<= 1) {
    de  += __shfl_xor(de,  msk);
    dp  += __shfl_xor(dp,  msk);
    dp2 += __shfl_xor(dp2, msk);
  }
  {
    double* es = (double*)&sm[OFF_ESUM];
    if (lane == 0) { es[wv*4+0] = de; es[wv*4+1] = dp; es[wv*4+2] = dp2; }
  }
  __syncthreads();
  if (tid == 0) {
    double* es = (double*)&sm[OFF_ESUM];
    double a = 0, b = 0, c = 0;
    for (int w = 0; w < 8; ++w) { a += es[w*4]; b += es[w*4+1]; c += es[w*4+2]; }
    wsd[(size_t)blockIdx.x*WS_STRIDE + 126] = a;
    wsd[(size_t)blockIdx.x*WS_STRIDE + 127] = b;
    wsd[(size_t)blockIdx.x*WS_STRIDE + 128] = c;
  }
}

extern "C" __global__ void finalize_kernel(double* __restrict__ wsd,
                                           float* __restrict__ out)
{
  const int t = threadIdx.x;
  if (t < 63) {
    double a = 0.0, b = 0.0;
    for (int blk = 0; blk < NBLK; ++blk) {
      a += wsd[(size_t)blk*WS_STRIDE + t*2 + 0];
      b += wsd[(size_t)blk*WS_STRIDE + t*2 + 1];
    }
    const double mean = a / (double)MC;
    const double var  = (b - a*a/(double)MC) / (double)(MC - 1);
    out[PV_OFF + t] = (float)mean;
    out[VV_OFF + t] = (float)var;
  } else if (t == 64) {
    double a = 0.0;
    for (int blk = 0; blk < NBLK; ++blk) a += wsd[(size_t)blk*WS_STRIDE + 126];
    wsd[MEANE_SLOT] = a / (double)MC;
  } else if (t == 65) {
    double a = 0.0, c = 0.0;
    for (int blk = 0; blk < NBLK; ++blk) {
      a += wsd[(size_t)blk*WS_STRIDE + 127];
      c += wsd[(size_t)blk*WS_STRIDE + 128];
    }
    out[MEAN_OFF] = (float)(a / (double)MC);
    out[VAR_OFF]  = (float)((c - a*a/(double)MC) / (double)(MC - 1));
  }
}

extern "C" __global__ void error_kernel(const double* __restrict__ wsd,
                                        float* __restrict__ out)
{
  const int pth = blockIdx.x * 256 + threadIdx.x;
  if (pth < MC) {
    const float meanE = (float)wsd[MEANE_SLOT];
    out[ERR_OFF + pth] = out[EP_OFF + pth] - meanE;
  }
}

extern "C" void kernel_launch(void* const* d_in, const int* in_sizes, int n_in,
                              void* d_out, int out_size, void* d_ws, size_t ws_size,
                              hipStream_t stream)
{
  (void)in_sizes; (void)n_in; (void)out_size; (void)ws_size;
  const float* S0g  = (const float*)d_in[0];
  const float* zg   = (const float*)d_in[1];
  // d_in[2..4] = MC_samples / ind_T / period_length (fixed constants)
  const float* dWi  = (const float*)d_in[5];
  const float* dbi  = (const float*)d_in[6];
  const float* dWh  = (const float*)d_in[7];
  const float* dbh  = (const float*)d_in[8];
  const float* dWo  = (const float*)d_in[9];
  const float* dbo  = (const float*)d_in[10];
  const float* vWi  = (const float*)d_in[11];
  const float* vbi  = (const float*)d_in[12];
  const float* vWh  = (const float*)d_in[13];
  const float* vbh  = (const float*)d_in[14];
  const float* vWo  = (const float*)d_in[15];
  const float* vbo  = (const float*)d_in[16];
  const float* eWi  = (const float*)d_in[17];
  const float* ebi  = (const float*)d_in[18];
  const float* eWh  = (const float*)d_in[19];
  const float* ebh  = (const float*)d_in[20];
  const float* eWo  = (const float*)d_in[21];
  const float* ebo  = (const float*)d_in[22];
  float* out  = (float*)d_out;
  double* wsd = (double*)d_ws;

  hipFuncSetAttribute(reinterpret_cast<const void*>(sim_kernel),
                      hipFuncAttributeMaxDynamicSharedMemorySize, SMEM_BYTES);

  sim_kernel<<<NBLK, TPB, SMEM_BYTES, stream>>>(
      S0g, zg, dWi, dbi, dWh, dbh, dWo, dbo,
      vWi, vbi, vWh, vbh, vWo, vbo,
      eWi, ebi, eWh, ebh, eWo, ebo, out, wsd);
  finalize_kernel<<<1, 128, 0, stream>>>(wsd, out);
  error_kernel<<<MC/256, 256, 0, stream>>>(wsd, out);
}